// Round 1
// baseline (182.043 us; speedup 1.0000x reference)
//
#include <hip/hip_runtime.h>

#define N_SAMPLES 65536
#define C_CLASSES 256
#define D_DIM     1024
#define ALPHA_C   1.0f
#define GAMMA_C   0.01f
#define SPLIT     8   // blocks per class in main kernel

// ---------------------------------------------------------------------------
// K1: sq[c] = sum_d cluster[c][d]^2.  One wave per class.
__global__ __launch_bounds__(64) void sq_kernel(const float* __restrict__ cluster,
                                                float* __restrict__ sq) {
    int c = blockIdx.x;
    int lane = threadIdx.x;
    const float4* row = (const float4*)(cluster + (size_t)c * D_DIM);
    float s = 0.f;
#pragma unroll
    for (int j = 0; j < 4; ++j) {
        float4 v = row[j * 64 + lane];
        s += v.x * v.x + v.y * v.y + v.z * v.z + v.w * v.w;
    }
#pragma unroll
    for (int m = 32; m >= 1; m >>= 1) s += __shfl_xor(s, m, 64);
    if (lane == 0) sq[c] = s;
}

// ---------------------------------------------------------------------------
// K2: denom[c] = sum_j relu(sq[c]+sq[j]-2*dot(c,j)) + ALPHA.
// Block handles 4 classes c0..c0+3 (staged in LDS); thread t owns column j=t.
__global__ __launch_bounds__(256) void denom_kernel(const float* __restrict__ cluster,
                                                    const float* __restrict__ sq,
                                                    float* __restrict__ denom) {
    __shared__ alignas(16) float a[4][D_DIM];     // 16 KB
    __shared__ float pairlds[4][256];             // 4 KB
    int c0 = blockIdx.x * 4;
    int t = threadIdx.x;
    {   // cooperative load of 4 cluster rows into LDS
        const float4* src = (const float4*)(cluster + (size_t)c0 * D_DIM);
        float4* dst = (float4*)&a[0][0];
#pragma unroll
        for (int j = 0; j < 4; ++j) dst[j * 256 + t] = src[j * 256 + t];
    }
    __syncthreads();
    const float4* brow = (const float4*)(cluster + (size_t)t * D_DIM);
    const float4* arows = (const float4*)&a[0][0];
    float dot[4] = {0.f, 0.f, 0.f, 0.f};
    for (int kk = 0; kk < 256; ++kk) {
        float4 b = brow[kk];
#pragma unroll
        for (int cc = 0; cc < 4; ++cc) {
            float4 av = arows[cc * 256 + kk];
            dot[cc] += av.x * b.x + av.y * b.y + av.z * b.z + av.w * b.w;
        }
    }
    float sqj = sq[t];
#pragma unroll
    for (int cc = 0; cc < 4; ++cc) {
        float p = sq[c0 + cc] + sqj - 2.f * dot[cc];
        pairlds[cc][t] = p > 0.f ? p : 0.f;
    }
    __syncthreads();
    int w = t >> 6, lane = t & 63;
    float s = pairlds[w][lane] + pairlds[w][lane + 64] +
              pairlds[w][lane + 128] + pairlds[w][lane + 192];
#pragma unroll
    for (int m = 32; m >= 1; m >>= 1) s += __shfl_xor(s, m, 64);
    if (lane == 0) denom[c0 + w] = s + ALPHA_C;
}

// ---------------------------------------------------------------------------
// K3a: per-class histogram.
__global__ __launch_bounds__(256) void count_kernel(const int* __restrict__ labels,
                                                    int lab_stride,
                                                    int* __restrict__ counts) {
    int i = blockIdx.x * 256 + threadIdx.x;
    if (i < N_SAMPLES) atomicAdd(&counts[labels[(size_t)i * lab_stride]], 1);
}

// K3b: serial exclusive prefix (256 elements, trivial).
__global__ void scan_kernel(const int* __restrict__ counts,
                            int* __restrict__ offsets, int* __restrict__ cursor) {
    if (threadIdx.x == 0 && blockIdx.x == 0) {
        int acc = 0;
        for (int c = 0; c < C_CLASSES; ++c) {
            offsets[c] = acc; cursor[c] = acc; acc += counts[c];
        }
        offsets[C_CLASSES] = acc;
    }
}

// K3c: scatter sample indices into per-class buckets.
__global__ __launch_bounds__(256) void scatter_kernel(const int* __restrict__ labels,
                                                      int lab_stride,
                                                      int* __restrict__ cursor,
                                                      int* __restrict__ bucket) {
    int i = blockIdx.x * 256 + threadIdx.x;
    if (i < N_SAMPLES) {
        int c = labels[(size_t)i * lab_stride];
        int pos = atomicAdd(&cursor[c], 1);
        bucket[pos] = i;
    }
}

// ---------------------------------------------------------------------------
// K4: main streaming kernel. Block (c, split); wave owns whole samples.
// Per sample: nume (wave shuffle-reduce) -> loss; diff-sum accumulated in regs.
// Block-end: combine 4 waves in LDS, atomicAdd into out_cluster (8 per addr).
__global__ __launch_bounds__(256) void main_kernel(const float* __restrict__ features,
                                                   const float* __restrict__ cluster,
                                                   const float* __restrict__ cw,
                                                   const float* __restrict__ denom,
                                                   const int* __restrict__ offsets,
                                                   const int* __restrict__ bucket,
                                                   float* __restrict__ loss_out,
                                                   float* __restrict__ out_cluster) {
    __shared__ alignas(16) float lds[4][D_DIM];   // 16 KB
    int c = blockIdx.x >> 3;
    int split = blockIdx.x & (SPLIT - 1);
    int w = threadIdx.x >> 6, lane = threadIdx.x & 63;
    int ws_id = split * 4 + w;                    // 0..31 wave slot within class

    const float4* crow = (const float4*)(cluster + (size_t)c * D_DIM);
    float4 ck[4];
#pragma unroll
    for (int j = 0; j < 4; ++j) ck[j] = crow[j * 64 + lane];

    float inv_dnm = 1.0f / denom[c];
    float4 dsum[4];
#pragma unroll
    for (int j = 0; j < 4; ++j) dsum[j] = make_float4(0.f, 0.f, 0.f, 0.f);

    int start = offsets[c], end = offsets[c + 1];
    for (int k = start + ws_id; k < end; k += SPLIT * 4) {
        int i = bucket[k];
        const float4* frow = (const float4*)(features + (size_t)i * D_DIM);
        float nume = 0.f;
#pragma unroll
        for (int j = 0; j < 4; ++j) {
            float4 f = frow[j * 64 + lane];
            float dx = f.x - ck[j].x, dy = f.y - ck[j].y;
            float dz = f.z - ck[j].z, dw = f.w - ck[j].w;
            dsum[j].x += dx; dsum[j].y += dy; dsum[j].z += dz; dsum[j].w += dw;
            nume += dx * dx + dy * dy + dz * dz + dw * dw;
        }
#pragma unroll
        for (int m = 32; m >= 1; m >>= 1) nume += __shfl_xor(nume, m, 64);
        if (lane == 0) loss_out[i] = nume * inv_dnm;
    }

    float4* ldsrow = (float4*)lds[w];
#pragma unroll
    for (int j = 0; j < 4; ++j) ldsrow[j * 64 + lane] = dsum[j];
    __syncthreads();

    float sc = GAMMA_C * cw[c] * inv_dnm;
    int t = threadIdx.x;                          // columns 4t..4t+3
    float4 v0 = ((const float4*)lds[0])[t];
    float4 v1 = ((const float4*)lds[1])[t];
    float4 v2 = ((const float4*)lds[2])[t];
    float4 v3 = ((const float4*)lds[3])[t];
    float* outc = out_cluster + (size_t)c * D_DIM + 4 * t;
    atomicAdd(outc + 0, -sc * (v0.x + v1.x + v2.x + v3.x));
    atomicAdd(outc + 1, -sc * (v0.y + v1.y + v2.y + v3.y));
    atomicAdd(outc + 2, -sc * (v0.z + v1.z + v2.z + v3.z));
    atomicAdd(outc + 3, -sc * (v0.w + v1.w + v2.w + v3.w));
}

// ---------------------------------------------------------------------------
extern "C" void kernel_launch(void* const* d_in, const int* in_sizes, int n_in,
                              void* d_out, int out_size, void* d_ws, size_t ws_size,
                              hipStream_t stream) {
    const float* features = (const float*)d_in[0];
    const int*   labels   = (const int*)d_in[1];
    const float* cluster  = (const float*)d_in[2];
    const float* cw       = (const float*)d_in[3];
    int lab_stride = in_sizes[1] / N_SAMPLES;   // 1 if int32, 2 if int64 words
    if (lab_stride < 1) lab_stride = 1;

    float* loss_out    = (float*)d_out;                 // N floats
    float* out_cluster = (float*)d_out + N_SAMPLES;     // C*D floats

    char* ws = (char*)d_ws;
    float* sq      = (float*)(ws);          // 256 f32
    float* denom   = (float*)(ws + 1024);   // 256 f32
    int*   counts  = (int*)  (ws + 2048);   // 256 i32
    int*   offsets = (int*)  (ws + 3072);   // 257 i32
    int*   cursor  = (int*)  (ws + 4352);   // 256 i32
    int*   bucket  = (int*)  (ws + 8192);   // 65536 i32

    hipMemsetAsync(counts, 0, C_CLASSES * sizeof(int), stream);
    hipMemcpyAsync(out_cluster, cluster, (size_t)C_CLASSES * D_DIM * sizeof(float),
                   hipMemcpyDeviceToDevice, stream);

    sq_kernel<<<C_CLASSES, 64, 0, stream>>>(cluster, sq);
    denom_kernel<<<C_CLASSES / 4, 256, 0, stream>>>(cluster, sq, denom);
    count_kernel<<<N_SAMPLES / 256, 256, 0, stream>>>(labels, lab_stride, counts);
    scan_kernel<<<1, 64, 0, stream>>>(counts, offsets, cursor);
    scatter_kernel<<<N_SAMPLES / 256, 256, 0, stream>>>(labels, lab_stride, cursor, bucket);
    main_kernel<<<C_CLASSES * SPLIT, 256, 0, stream>>>(features, cluster, cw, denom,
                                                       offsets, bucket, loss_out, out_cluster);
}

// Round 2
// 162.358 us; speedup vs baseline: 1.1212x; 1.1212x over previous
//
#include <hip/hip_runtime.h>

#define N_SAMPLES 65536
#define C_CLASSES 256
#define D_DIM     1024
#define ALPHA_C   1.0f
#define GAMMA_C   0.01f
#define SPLIT     8            // blocks per class in main kernel
#define NDENOM_BLOCKS 64       // C/4

// ---------------------------------------------------------------------------
// prep: blocks [0,64) compute denom (with fused sq); blocks [64,320) do the
// label histogram AND copy cluster -> out_cluster (output init).
__global__ __launch_bounds__(256) void prep_kernel(const float* __restrict__ cluster,
                                                   const int* __restrict__ labels,
                                                   int lab_stride,
                                                   int* __restrict__ counts,
                                                   float* __restrict__ denom,
                                                   float* __restrict__ out_cluster) {
    int t = threadIdx.x;
    if (blockIdx.x >= NDENOM_BLOCKS) {
        int b = blockIdx.x - NDENOM_BLOCKS;          // 0..255
        int i = b * 256 + t;
        atomicAdd(&counts[labels[(size_t)i * lab_stride]], 1);
        ((float4*)out_cluster)[b * 256 + t] = ((const float4*)cluster)[b * 256 + t];
        return;
    }
    // ---- denom path: block handles classes c0..c0+3 ----
    __shared__ alignas(16) float a[4][D_DIM];        // 16 KB
    __shared__ float pairlds[4][256];                // 4 KB
    __shared__ float sqc[4];
    int c0 = blockIdx.x * 4;
    {
        const float4* src = (const float4*)(cluster + (size_t)c0 * D_DIM);
        float4* dst = (float4*)&a[0][0];
#pragma unroll
        for (int j = 0; j < 4; ++j) dst[j * 256 + t] = src[j * 256 + t];
    }
    __syncthreads();
    const float4* brow = (const float4*)(cluster + (size_t)t * D_DIM);
    const float4* arows = (const float4*)&a[0][0];
    float dot[4] = {0.f, 0.f, 0.f, 0.f};
    float sqj = 0.f;
    for (int kk = 0; kk < 256; ++kk) {
        float4 bv = brow[kk];
        sqj += bv.x * bv.x + bv.y * bv.y + bv.z * bv.z + bv.w * bv.w;
#pragma unroll
        for (int cc = 0; cc < 4; ++cc) {
            float4 av = arows[cc * 256 + kk];
            dot[cc] += av.x * bv.x + av.y * bv.y + av.z * bv.z + av.w * bv.w;
        }
    }
    int rel = t - c0;
    if (rel >= 0 && rel < 4) sqc[rel] = sqj;         // sq of the block's 4 rows
    __syncthreads();
#pragma unroll
    for (int cc = 0; cc < 4; ++cc) {
        float p = sqc[cc] + sqj - 2.f * dot[cc];
        pairlds[cc][t] = p > 0.f ? p : 0.f;
    }
    __syncthreads();
    int w = t >> 6, lane = t & 63;
    float s = pairlds[w][lane] + pairlds[w][lane + 64] +
              pairlds[w][lane + 128] + pairlds[w][lane + 192];
#pragma unroll
    for (int m = 32; m >= 1; m >>= 1) s += __shfl_xor(s, m, 64);
    if (lane == 0) denom[c0 + w] = s + ALPHA_C;
}

// ---------------------------------------------------------------------------
// scatter: wave-0 shuffle-scan of counts -> LDS offsets, then bucket scatter.
__global__ __launch_bounds__(256) void scatter_kernel(const int* __restrict__ labels,
                                                      int lab_stride,
                                                      const int* __restrict__ counts,
                                                      int* __restrict__ cursor,
                                                      int* __restrict__ bucket) {
    __shared__ int offs[C_CLASSES];
    int t = threadIdx.x;
    if (t < 64) {
        int4 c4 = ((const int4*)counts)[t];
        int local = c4.x + c4.y + c4.z + c4.w;
        int inc = local;
#pragma unroll
        for (int m = 1; m < 64; m <<= 1) {
            int o = __shfl_up(inc, m, 64);
            if (t >= m) inc += o;
        }
        int exc = inc - local;
        offs[4 * t + 0] = exc;
        offs[4 * t + 1] = exc + c4.x;
        offs[4 * t + 2] = exc + c4.x + c4.y;
        offs[4 * t + 3] = exc + c4.x + c4.y + c4.z;
    }
    __syncthreads();
    int i = blockIdx.x * 256 + t;
    int c = labels[(size_t)i * lab_stride];
    int pos = offs[c] + atomicAdd(&cursor[c], 1);
    bucket[pos] = i;
}

// ---------------------------------------------------------------------------
// main: block (c, split). Wave-0 recomputes this class's [start,end) from
// counts; waves stream whole samples (2 per iter), diff-sums in registers,
// LDS combine at end, 8 atomics per output element into out_cluster.
__global__ __launch_bounds__(256, 4) void main_kernel(const float* __restrict__ features,
                                                      const float* __restrict__ cluster,
                                                      const float* __restrict__ cw,
                                                      const float* __restrict__ denom,
                                                      const int* __restrict__ counts,
                                                      const int* __restrict__ bucket,
                                                      float* __restrict__ loss_out,
                                                      float* __restrict__ out_cluster) {
    __shared__ alignas(16) float lds[4][D_DIM];      // 16 KB
    __shared__ int range[2];
    int c = blockIdx.x >> 3;
    int split = blockIdx.x & (SPLIT - 1);
    int t = threadIdx.x;
    int w = t >> 6, lane = t & 63;

    if (t < 64) {
        int4 c4 = ((const int4*)counts)[t];
        int local = c4.x + c4.y + c4.z + c4.w;
        int inc = local;
#pragma unroll
        for (int m = 1; m < 64; m <<= 1) {
            int o = __shfl_up(inc, m, 64);
            if (t >= m) inc += o;
        }
        int exc = inc - local;
        int lc = c >> 2, rc = c & 3;
        if (t == lc) {
            int base = exc + (rc > 0 ? c4.x : 0) + (rc > 1 ? c4.y : 0) + (rc > 2 ? c4.z : 0);
            int cnt  = (rc == 0) ? c4.x : (rc == 1) ? c4.y : (rc == 2) ? c4.z : c4.w;
            range[0] = base;
            range[1] = base + cnt;
        }
    }
    __syncthreads();
    int start = range[0], end = range[1];

    const float4* crow = (const float4*)(cluster + (size_t)c * D_DIM);
    float4 ck[4];
#pragma unroll
    for (int j = 0; j < 4; ++j) ck[j] = crow[j * 64 + lane];

    float inv_dnm = 1.0f / denom[c];
    float4 dsum[4];
#pragma unroll
    for (int j = 0; j < 4; ++j) dsum[j] = make_float4(0.f, 0.f, 0.f, 0.f);

    const int STRIDE = SPLIT * 4;                    // 32 waves per class
    int k = start + split * 4 + w;
    for (; k + STRIDE < end; k += 2 * STRIDE) {
        int i0 = bucket[k], i1 = bucket[k + STRIDE];
        const float4* f0 = (const float4*)(features + (size_t)i0 * D_DIM);
        const float4* f1 = (const float4*)(features + (size_t)i1 * D_DIM);
        float4 v0[4], v1[4];
#pragma unroll
        for (int j = 0; j < 4; ++j) v0[j] = f0[j * 64 + lane];
#pragma unroll
        for (int j = 0; j < 4; ++j) v1[j] = f1[j * 64 + lane];
        float n0 = 0.f, n1 = 0.f;
#pragma unroll
        for (int j = 0; j < 4; ++j) {
            float dx = v0[j].x - ck[j].x, dy = v0[j].y - ck[j].y;
            float dz = v0[j].z - ck[j].z, dw = v0[j].w - ck[j].w;
            dsum[j].x += dx; dsum[j].y += dy; dsum[j].z += dz; dsum[j].w += dw;
            n0 += dx * dx + dy * dy + dz * dz + dw * dw;
        }
#pragma unroll
        for (int j = 0; j < 4; ++j) {
            float dx = v1[j].x - ck[j].x, dy = v1[j].y - ck[j].y;
            float dz = v1[j].z - ck[j].z, dw = v1[j].w - ck[j].w;
            dsum[j].x += dx; dsum[j].y += dy; dsum[j].z += dz; dsum[j].w += dw;
            n1 += dx * dx + dy * dy + dz * dz + dw * dw;
        }
#pragma unroll
        for (int m = 32; m >= 1; m >>= 1) {
            n0 += __shfl_xor(n0, m, 64);
            n1 += __shfl_xor(n1, m, 64);
        }
        if (lane == 0) {
            loss_out[i0] = n0 * inv_dnm;
            loss_out[i1] = n1 * inv_dnm;
        }
    }
    if (k < end) {
        int i0 = bucket[k];
        const float4* f0 = (const float4*)(features + (size_t)i0 * D_DIM);
        float n0 = 0.f;
#pragma unroll
        for (int j = 0; j < 4; ++j) {
            float4 v = f0[j * 64 + lane];
            float dx = v.x - ck[j].x, dy = v.y - ck[j].y;
            float dz = v.z - ck[j].z, dw = v.w - ck[j].w;
            dsum[j].x += dx; dsum[j].y += dy; dsum[j].z += dz; dsum[j].w += dw;
            n0 += dx * dx + dy * dy + dz * dz + dw * dw;
        }
#pragma unroll
        for (int m = 32; m >= 1; m >>= 1) n0 += __shfl_xor(n0, m, 64);
        if (lane == 0) loss_out[i0] = n0 * inv_dnm;
    }

    float4* ldsrow = (float4*)lds[w];
#pragma unroll
    for (int j = 0; j < 4; ++j) ldsrow[j * 64 + lane] = dsum[j];
    __syncthreads();

    float sc = GAMMA_C * cw[c] * inv_dnm;
    float4 u0 = ((const float4*)lds[0])[t];
    float4 u1 = ((const float4*)lds[1])[t];
    float4 u2 = ((const float4*)lds[2])[t];
    float4 u3 = ((const float4*)lds[3])[t];
    float* outc = out_cluster + (size_t)c * D_DIM + 4 * t;
    atomicAdd(outc + 0, -sc * (u0.x + u1.x + u2.x + u3.x));
    atomicAdd(outc + 1, -sc * (u0.y + u1.y + u2.y + u3.y));
    atomicAdd(outc + 2, -sc * (u0.z + u1.z + u2.z + u3.z));
    atomicAdd(outc + 3, -sc * (u0.w + u1.w + u2.w + u3.w));
}

// ---------------------------------------------------------------------------
extern "C" void kernel_launch(void* const* d_in, const int* in_sizes, int n_in,
                              void* d_out, int out_size, void* d_ws, size_t ws_size,
                              hipStream_t stream) {
    const float* features = (const float*)d_in[0];
    const int*   labels   = (const int*)d_in[1];
    const float* cluster  = (const float*)d_in[2];
    const float* cw       = (const float*)d_in[3];
    int lab_stride = in_sizes[1] / N_SAMPLES;   // 1 if int32 words, 2 if int64 words
    if (lab_stride < 1) lab_stride = 1;

    float* loss_out    = (float*)d_out;                 // N floats
    float* out_cluster = (float*)d_out + N_SAMPLES;     // C*D floats

    char* ws = (char*)d_ws;
    int*   counts = (int*)  (ws);           // 256 i32
    int*   cursor = (int*)  (ws + 1024);    // 256 i32
    float* denom  = (float*)(ws + 2048);    // 256 f32
    int*   bucket = (int*)  (ws + 4096);    // 65536 i32

    hipMemsetAsync(counts, 0, 2048, stream);   // counts + cursor

    prep_kernel<<<NDENOM_BLOCKS + N_SAMPLES / 256, 256, 0, stream>>>(
        cluster, labels, lab_stride, counts, denom, out_cluster);
    scatter_kernel<<<N_SAMPLES / 256, 256, 0, stream>>>(
        labels, lab_stride, counts, cursor, bucket);
    main_kernel<<<C_CLASSES * SPLIT, 256, 0, stream>>>(
        features, cluster, cw, denom, counts, bucket, loss_out, out_cluster);
}